// Round 4
// baseline (631.132 us; speedup 1.0000x reference)
//
#include <hip/hip_runtime.h>
#include <hip/hip_bf16.h>
#include <stdint.h>

#define D_MODEL 1024
#define NHEADS  16
#define DKH     64
#define SEQ     2048
#define BATCH   4
#define MTOT    (BATCH*SEQ)   // 8192

typedef unsigned short u16;
typedef uint32_t u32;
typedef __attribute__((ext_vector_type(8))) unsigned short us8;
typedef __attribute__((ext_vector_type(4))) float f32x4;
typedef __attribute__((ext_vector_type(16))) float f32x16;
typedef __attribute__((ext_vector_type(8))) __bf16 bf16x8;

#define LOG2E 1.4426950408889634f
#define QK_SCALE2 (0.125f * LOG2E)       // 1/sqrt(64) * log2(e)
#define MASK_SCALE2 (-1e9f * LOG2E)
#define RESC_THR 8.0f                    // defer-rescale threshold (log2 domain)

__device__ __forceinline__ u16 to_bf16(float f) {
  __bf16 h = (__bf16)f;            // RNE fptrunc
  return __builtin_bit_cast(u16, h);
}
__device__ __forceinline__ u32 pack_bf16(float lo, float hi) {
  return (u32)to_bf16(lo) | ((u32)to_bf16(hi) << 16);
}

__device__ __forceinline__ f32x4 mfma16(us8 a, us8 b, f32x4 c) {
  return __builtin_amdgcn_mfma_f32_16x16x32_bf16(
      __builtin_bit_cast(bf16x8, a), __builtin_bit_cast(bf16x8, b), c, 0, 0, 0);
}
__device__ __forceinline__ f32x16 mfma32(us8 a, us8 b, f32x16 c) {
  return __builtin_amdgcn_mfma_f32_32x32x16_bf16(
      __builtin_bit_cast(bf16x8, a), __builtin_bit_cast(bf16x8, b), c, 0, 0, 0);
}

__device__ __forceinline__ us8 cvt8(float4 x, float4 y) {
  us8 r;
  r[0] = to_bf16(x.x); r[1] = to_bf16(x.y); r[2] = to_bf16(x.z); r[3] = to_bf16(x.w);
  r[4] = to_bf16(y.x); r[5] = to_bf16(y.y); r[6] = to_bf16(y.z); r[7] = to_bf16(y.w);
  return r;
}

// ---------------- transpose+convert weight: W[K][N] f32 -> Wt[N][K] bf16 ----
__global__ __launch_bounds__(256) void transpose_cvt_w(
    const float* __restrict__ W, u16* __restrict__ Wt, int rows, int cols) {
  __shared__ float tile[32][33];
  const int c0 = blockIdx.x * 32, r0 = blockIdx.y * 32;
  const int tx = threadIdx.x & 31, ty = threadIdx.x >> 5;
#pragma unroll
  for (int yy = ty; yy < 32; yy += 8)
    tile[yy][tx] = W[(size_t)(r0 + yy) * cols + c0 + tx];
  __syncthreads();
#pragma unroll
  for (int yy = ty; yy < 32; yy += 8)
    Wt[(size_t)(c0 + yy) * rows + r0 + tx] = to_bf16(tile[tx][yy]);
}

// ---------------- transpose V: per b, Vp[S][1024] bf16 -> Vt[1024][S] bf16 --
__global__ __launch_bounds__(256) void transpose_v_kernel(
    const u16* __restrict__ Vp, u16* __restrict__ Vt) {
  __shared__ u16 tile[32][33];
  const int b = blockIdx.z;
  const int c0 = blockIdx.x * 32, r0 = blockIdx.y * 32;
  const u16* in = Vp + (size_t)b * SEQ * D_MODEL;
  u16* out = Vt + (size_t)b * D_MODEL * SEQ;
  const int tx = threadIdx.x & 31, ty = threadIdx.x >> 5;
#pragma unroll
  for (int yy = ty; yy < 32; yy += 8)
    tile[yy][tx] = in[(size_t)(r0 + yy) * D_MODEL + c0 + tx];
  __syncthreads();
#pragma unroll
  for (int yy = ty; yy < 32; yy += 8)
    out[(size_t)(c0 + yy) * SEQ + r0 + tx] = tile[tx][yy];
}

// ---------------- GEMM: C[M][N] = A[M][K] * Bt[N][K]^T + bias --------------
template <bool AF32, bool F32OUT>
__global__ __launch_bounds__(256) void gemm_bt(
    const void* __restrict__ Av, const u16* __restrict__ Bt,
    const float* __restrict__ bias, void* __restrict__ Cv, int N, int K) {
  __shared__ __align__(16) u16 As[128][32];
  __shared__ __align__(16) u16 Bs[128][32];
  const int m0 = blockIdx.x * 128, n0 = blockIdx.y * 128;
  const int t = threadIdx.x;
  const int lane = t & 63, wave = t >> 6;
  const int wm = wave >> 1, wn = wave & 1;
  const int lrow = lane & 15, lhalf = lane >> 4;
  const int r0 = t >> 2, o0 = (t & 3) << 3;

  f32x4 acc[4][4];
#pragma unroll
  for (int i = 0; i < 4; i++)
#pragma unroll
    for (int j = 0; j < 4; j++) acc[i][j] = (f32x4){0.f, 0.f, 0.f, 0.f};

  for (int k0 = 0; k0 < K; k0 += 32) {
    us8 a0, a1, b0, b1;
    if constexpr (AF32) {
      const float* Af = (const float*)Av;
      const float4* p0 = (const float4*)(Af + (size_t)(m0 + r0) * K + k0 + o0);
      const float4* p1 = (const float4*)(Af + (size_t)(m0 + r0 + 64) * K + k0 + o0);
      a0 = cvt8(p0[0], p0[1]);
      a1 = cvt8(p1[0], p1[1]);
    } else {
      const u16* Ab = (const u16*)Av;
      a0 = *(const us8*)(Ab + (size_t)(m0 + r0) * K + k0 + o0);
      a1 = *(const us8*)(Ab + (size_t)(m0 + r0 + 64) * K + k0 + o0);
    }
    b0 = *(const us8*)(Bt + (size_t)(n0 + r0) * K + k0 + o0);
    b1 = *(const us8*)(Bt + (size_t)(n0 + r0 + 64) * K + k0 + o0);
    __syncthreads();
    *(us8*)(&As[r0][o0]) = a0;
    *(us8*)(&As[r0 + 64][o0]) = a1;
    *(us8*)(&Bs[r0][o0]) = b0;
    *(us8*)(&Bs[r0 + 64][o0]) = b1;
    __syncthreads();
    us8 af[4], bfr[4];
#pragma unroll
    for (int i = 0; i < 4; i++)
      af[i] = *(const us8*)(&As[wm * 64 + i * 16 + lrow][lhalf * 8]);
#pragma unroll
    for (int j = 0; j < 4; j++)
      bfr[j] = *(const us8*)(&Bs[wn * 64 + j * 16 + lrow][lhalf * 8]);
#pragma unroll
    for (int i = 0; i < 4; i++)
#pragma unroll
      for (int j = 0; j < 4; j++) acc[i][j] = mfma16(af[i], bfr[j], acc[i][j]);
  }

#pragma unroll
  for (int i = 0; i < 4; i++) {
    const int rowb = m0 + wm * 64 + i * 16 + lhalf * 4;
#pragma unroll
    for (int j = 0; j < 4; j++) {
      const int col = n0 + wn * 64 + j * 16 + lrow;
      const float bv = bias[col];
#pragma unroll
      for (int r = 0; r < 4; r++) {
        float v = acc[i][j][r] + bv;
        if constexpr (F32OUT)
          ((float*)Cv)[(size_t)(rowb + r) * N + col] = v;
        else
          ((u16*)Cv)[(size_t)(rowb + r) * N + col] = to_bf16(v);
      }
    }
  }
}

// ---------------- flash attention, swapped-QK^T 32x32 ----------------------
// 4 waves/block; wave w owns q-rows [bx*128 + w*32, +32) of head (b,h).
// Lane owns q = lane&31; lane and lane^32 hold complementary kv halves.
// S^T = mfma32(K, Q); O^T = mfma32(V^T, P^T). Softmax in exp2 domain,
// defer-rescale (T13), next-K register prefetch + early V/mask issue (T14).
__global__ __launch_bounds__(256) void attn_fwd(
    const u16* __restrict__ Qp, const u16* __restrict__ Kp,
    const u16* __restrict__ Vt, const float* __restrict__ mask,
    u16* __restrict__ ctx) {
  const int b = blockIdx.z, h = blockIdx.y;
  const int t = threadIdx.x;
  const int wave = t >> 6, lane = t & 63;
  const int l31 = lane & 31, hi = lane >> 5;
  const int q0 = blockIdx.x * 128 + wave * 32;

  __shared__ __align__(16) u16 Plds[4][32][72];  // per-wave slice

  const u16* Qb = Qp + (size_t)(b * SEQ + q0) * D_MODEL + h * DKH;
  const u16* Kb = Kp + (size_t)(b * SEQ) * D_MODEL + h * DKH;
  const u16* Vb = Vt + (size_t)(b * NHEADS + h) * DKH * SEQ;
  const float* mb = mask + (size_t)b * SEQ;

  us8 qf[4];
#pragma unroll
  for (int s = 0; s < 4; s++)
    qf[s] = *(const us8*)(Qb + (size_t)l31 * D_MODEL + s * 16 + hi * 8);

  float mrow = -1e30f, lsum = 0.f;
  f32x16 o0 = {}, o1 = {};

  // prefetch K for tile 0
  us8 kpf[4];
#pragma unroll
  for (int s = 0; s < 4; s++)
    kpf[s] = *(const us8*)(Kb + (size_t)l31 * D_MODEL + s * 16 + hi * 8);

  for (int j0 = 0; j0 < SEQ; j0 += 32) {
    // current K = prefetched
    us8 kf[4];
#pragma unroll
    for (int s = 0; s < 4; s++) kf[s] = kpf[s];
    // issue next-tile K loads (off critical path; covered by this tile's work)
    if (j0 + 32 < SEQ) {
      const u16* kn = Kb + (size_t)(j0 + 32 + l31) * D_MODEL;
#pragma unroll
      for (int s = 0; s < 4; s++)
        kpf[s] = *(const us8*)(kn + s * 16 + hi * 8);
    }
    // issue V + mask for this tile early (QK^T + softmax cover their latency)
    us8 vf00 = *(const us8*)(Vb + (size_t)l31 * SEQ + j0 + hi * 8);
    us8 vf01 = *(const us8*)(Vb + (size_t)l31 * SEQ + j0 + 16 + hi * 8);
    us8 vf10 = *(const us8*)(Vb + (size_t)(32 + l31) * SEQ + j0 + hi * 8);
    us8 vf11 = *(const us8*)(Vb + (size_t)(32 + l31) * SEQ + j0 + 16 + hi * 8);
    float4 mq[4];
#pragma unroll
    for (int t2 = 0; t2 < 4; t2++)
      mq[t2] = *(const float4*)(mb + j0 + 8 * t2 + 4 * hi);

    // S^T[kv][q], dk = 64 -> 4 MFMAs
    f32x16 st = {};
#pragma unroll
    for (int s = 0; s < 4; s++) st = mfma32(kf[s], qf[s], st);

    // logits in log2 domain; lane's kv(r) = (r&3) + 8*(r>>2) + 4*hi
    float sc[16];
#pragma unroll
    for (int r = 0; r < 16; r++) {
      const float* mqf = (const float*)&mq[r >> 2];
      sc[r] = fmaf(st[r], QK_SCALE2, mqf[r & 3] * MASK_SCALE2);
    }
    // max: in-lane tree + one cross-half shfl
    float mx = fmaxf(fmaxf(fmaxf(fmaxf(sc[0], sc[1]), fmaxf(sc[2], sc[3])),
                           fmaxf(fmaxf(sc[4], sc[5]), fmaxf(sc[6], sc[7]))),
                     fmaxf(fmaxf(fmaxf(sc[8], sc[9]), fmaxf(sc[10], sc[11])),
                           fmaxf(fmaxf(sc[12], sc[13]), fmaxf(sc[14], sc[15]))));
    mx = fmaxf(mx, __shfl_xor(mx, 32));
    // defer-rescale: only pay the O-rescale when max grew past THR
    if (!__all(mx <= mrow + RESC_THR)) {
      const float mnew = fmaxf(mrow, mx);
      const float corr = __builtin_exp2f(mrow - mnew);
      mrow = mnew;
      lsum *= corr;
#pragma unroll
      for (int r = 0; r < 16; r++) { o0[r] *= corr; o1[r] *= corr; }
    }
    // exp2 + sum (p bounded by 2^THR when deferred)
    float p[16];
#pragma unroll
    for (int r = 0; r < 16; r++) p[r] = __builtin_exp2f(sc[r] - mrow);
    float rs = (((p[0] + p[1]) + (p[2] + p[3])) + ((p[4] + p[5]) + (p[6] + p[7])))
             + (((p[8] + p[9]) + (p[10] + p[11])) + ((p[12] + p[13]) + (p[14] + p[15])));
    rs += __shfl_xor(rs, 32);
    lsum += rs;
    // P^T -> B-fragments: pack bf16 pairs, cross-half shfl, select
    u32 w[8], sw[8];
#pragma unroll
    for (int tt = 0; tt < 8; tt++) w[tt] = pack_bf16(p[2 * tt], p[2 * tt + 1]);
#pragma unroll
    for (int tt = 0; tt < 8; tt++) sw[tt] = (u32)__shfl_xor((int)w[tt], 32);
    union { u32 uw[4]; us8 v; } pb0, pb1;
    pb0.uw[0] = hi ? sw[2] : w[0];  pb0.uw[1] = hi ? sw[3] : w[1];
    pb0.uw[2] = hi ? w[2] : sw[0];  pb0.uw[3] = hi ? w[3] : sw[1];
    pb1.uw[0] = hi ? sw[6] : w[4];  pb1.uw[1] = hi ? sw[7] : w[5];
    pb1.uw[2] = hi ? w[6] : sw[4];  pb1.uw[3] = hi ? w[7] : sw[5];
    // O^T += V^T · P^T
    o0 = mfma32(vf00, pb0.v, o0);
    o0 = mfma32(vf01, pb1.v, o0);
    o1 = mfma32(vf10, pb0.v, o1);
    o1 = mfma32(vf11, pb1.v, o1);
  }

  const float inv = 1.0f / lsum;
  // O^T -> LDS; lane's d(r) = db*32 + (r&3) + 8*(r>>2) + 4*hi (pairs r=2t,2t+1)
#pragma unroll
  for (int tt = 0; tt < 8; tt++) {
    const int r = 2 * tt;
    const int d0 = (r & 3) + 8 * (r >> 2) + 4 * hi;
    *(u32*)&Plds[wave][l31][d0]      = pack_bf16(o0[r] * inv, o0[r + 1] * inv);
    *(u32*)&Plds[wave][l31][32 + d0] = pack_bf16(o1[r] * inv, o1[r + 1] * inv);
  }
  __syncthreads();
  u16* op = ctx + (size_t)(b * SEQ + q0) * D_MODEL + h * DKH;
#pragma unroll
  for (int pass = 0; pass < 4; pass++) {
    const int row = pass * 8 + (lane >> 3);
    const int c = (lane & 7) * 8;
    us8 vv = *(const us8*)&Plds[wave][row][c];
    *(us8*)(op + (size_t)row * D_MODEL + c) = vv;
  }
}

// ---------------------------------------------------------------------------
extern "C" void kernel_launch(void* const* d_in, const int* in_sizes, int n_in,
                              void* d_out, int out_size, void* d_ws, size_t ws_size,
                              hipStream_t stream) {
  const float* query = (const float*)d_in[0];
  const float* key   = (const float*)d_in[1];
  const float* value = (const float*)d_in[2];
  const float* mask  = (const float*)d_in[3];
  const float* Wq = (const float*)d_in[4];  const float* bq = (const float*)d_in[5];
  const float* Wk = (const float*)d_in[6];  const float* bk = (const float*)d_in[7];
  const float* Wv = (const float*)d_in[8];  const float* bv = (const float*)d_in[9];
  const float* Wo = (const float*)d_in[10]; const float* bo = (const float*)d_in[11];
  float* out = (float*)d_out;

  const size_t MB = 1ull << 20;
  char* ws = (char*)d_ws;
  u16* wtq = (u16*)(ws + 0 * MB);
  u16* wtk = (u16*)(ws + 2 * MB);
  u16* wtv = (u16*)(ws + 4 * MB);
  u16* wto = (u16*)(ws + 6 * MB);
  u16* Qp  = (u16*)(ws + 8 * MB);
  u16* Kp  = (u16*)(ws + 24 * MB);
  u16* ctx = (u16*)(ws + 40 * MB);
  u16* Vp = (u16*)d_out;                         // dead before final GEMM
  u16* Vt = Vp + (size_t)MTOT * D_MODEL;

  transpose_cvt_w<<<dim3(32, 32), 256, 0, stream>>>(Wq, wtq, D_MODEL, D_MODEL);
  transpose_cvt_w<<<dim3(32, 32), 256, 0, stream>>>(Wk, wtk, D_MODEL, D_MODEL);
  transpose_cvt_w<<<dim3(32, 32), 256, 0, stream>>>(Wv, wtv, D_MODEL, D_MODEL);
  transpose_cvt_w<<<dim3(32, 32), 256, 0, stream>>>(Wo, wto, D_MODEL, D_MODEL);

  dim3 ggrid(MTOT / 128, D_MODEL / 128);
  gemm_bt<true, false><<<ggrid, 256, 0, stream>>>((const void*)query, wtq, bq, (void*)Qp, D_MODEL, D_MODEL);
  gemm_bt<true, false><<<ggrid, 256, 0, stream>>>((const void*)key,   wtk, bk, (void*)Kp, D_MODEL, D_MODEL);
  gemm_bt<true, false><<<ggrid, 256, 0, stream>>>((const void*)value, wtv, bv, (void*)Vp, D_MODEL, D_MODEL);

  transpose_v_kernel<<<dim3(D_MODEL / 32, SEQ / 32, BATCH), 256, 0, stream>>>(Vp, Vt);

  attn_fwd<<<dim3(SEQ / 128, NHEADS, BATCH), 256, 0, stream>>>(Qp, Kp, Vt, mask, ctx);

  gemm_bt<false, true><<<ggrid, 256, 0, stream>>>((const void*)ctx, wto, bo, (void*)out, D_MODEL, D_MODEL);
}

// Round 6
// 459.227 us; speedup vs baseline: 1.3743x; 1.3743x over previous
//
#include <hip/hip_runtime.h>
#include <hip/hip_bf16.h>
#include <stdint.h>

#define D_MODEL 1024
#define NHEADS  16
#define DKH     64
#define SEQ     2048
#define BATCH   4
#define MTOT    (BATCH*SEQ)   // 8192

typedef unsigned short u16;
typedef uint32_t u32;
typedef __attribute__((ext_vector_type(8))) unsigned short us8;
typedef __attribute__((ext_vector_type(4))) float f32x4;
typedef __attribute__((ext_vector_type(16))) float f32x16;
typedef __attribute__((ext_vector_type(8))) __bf16 bf16x8;

#define LOG2E 1.4426950408889634f
#define QK_SCALE2 (0.125f * LOG2E)       // 1/sqrt(64) * log2(e)
#define MASK_SCALE2 (-1e9f * LOG2E)
#define RESC_THR 8.0f                    // defer-rescale threshold (log2 domain)

__device__ __forceinline__ u16 to_bf16(float f) {
  __bf16 h = (__bf16)f;            // RNE fptrunc
  return __builtin_bit_cast(u16, h);
}
__device__ __forceinline__ u32 pack_bf16(float lo, float hi) {
  return (u32)to_bf16(lo) | ((u32)to_bf16(hi) << 16);
}

__device__ __forceinline__ f32x4 mfma16(us8 a, us8 b, f32x4 c) {
  return __builtin_amdgcn_mfma_f32_16x16x32_bf16(
      __builtin_bit_cast(bf16x8, a), __builtin_bit_cast(bf16x8, b), c, 0, 0, 0);
}
__device__ __forceinline__ f32x16 mfma32(us8 a, us8 b, f32x16 c) {
  return __builtin_amdgcn_mfma_f32_32x32x16_bf16(
      __builtin_bit_cast(bf16x8, a), __builtin_bit_cast(bf16x8, b), c, 0, 0, 0);
}

__device__ __forceinline__ us8 cvt8(float4 x, float4 y) {
  us8 r;
  r[0] = to_bf16(x.x); r[1] = to_bf16(x.y); r[2] = to_bf16(x.z); r[3] = to_bf16(x.w);
  r[4] = to_bf16(y.x); r[5] = to_bf16(y.y); r[6] = to_bf16(y.z); r[7] = to_bf16(y.w);
  return r;
}

// ---------------- transpose+convert weight: W[K][N] f32 -> Wt[N][K] bf16 ----
__global__ __launch_bounds__(256) void transpose_cvt_w(
    const float* __restrict__ W, u16* __restrict__ Wt, int rows, int cols) {
  __shared__ float tile[32][33];
  const int c0 = blockIdx.x * 32, r0 = blockIdx.y * 32;
  const int tx = threadIdx.x & 31, ty = threadIdx.x >> 5;
#pragma unroll
  for (int yy = ty; yy < 32; yy += 8)
    tile[yy][tx] = W[(size_t)(r0 + yy) * cols + c0 + tx];
  __syncthreads();
#pragma unroll
  for (int yy = ty; yy < 32; yy += 8)
    Wt[(size_t)(c0 + yy) * rows + r0 + tx] = to_bf16(tile[tx][yy]);
}

// ---------------- transpose V: per b, Vp[S][1024] bf16 -> Vt[1024][S] bf16 --
__global__ __launch_bounds__(256) void transpose_v_kernel(
    const u16* __restrict__ Vp, u16* __restrict__ Vt) {
  __shared__ u16 tile[32][33];
  const int b = blockIdx.z;
  const int c0 = blockIdx.x * 32, r0 = blockIdx.y * 32;
  const u16* in = Vp + (size_t)b * SEQ * D_MODEL;
  u16* out = Vt + (size_t)b * D_MODEL * SEQ;
  const int tx = threadIdx.x & 31, ty = threadIdx.x >> 5;
#pragma unroll
  for (int yy = ty; yy < 32; yy += 8)
    tile[yy][tx] = in[(size_t)(r0 + yy) * D_MODEL + c0 + tx];
  __syncthreads();
#pragma unroll
  for (int yy = ty; yy < 32; yy += 8)
    out[(size_t)(c0 + yy) * SEQ + r0 + tx] = tile[tx][yy];
}

// ---------------- GEMM: C[M][N] = A[M][K] * Bt[N][K]^T + bias --------------
template <bool AF32, bool F32OUT>
__global__ __launch_bounds__(256) void gemm_bt(
    const void* __restrict__ Av, const u16* __restrict__ Bt,
    const float* __restrict__ bias, void* __restrict__ Cv, int N, int K) {
  __shared__ __align__(16) u16 As[128][32];
  __shared__ __align__(16) u16 Bs[128][32];
  const int m0 = blockIdx.x * 128, n0 = blockIdx.y * 128;
  const int t = threadIdx.x;
  const int lane = t & 63, wave = t >> 6;
  const int wm = wave >> 1, wn = wave & 1;
  const int lrow = lane & 15, lhalf = lane >> 4;
  const int r0 = t >> 2, o0 = (t & 3) << 3;

  f32x4 acc[4][4];
#pragma unroll
  for (int i = 0; i < 4; i++)
#pragma unroll
    for (int j = 0; j < 4; j++) acc[i][j] = (f32x4){0.f, 0.f, 0.f, 0.f};

  for (int k0 = 0; k0 < K; k0 += 32) {
    us8 a0, a1, b0, b1;
    if constexpr (AF32) {
      const float* Af = (const float*)Av;
      const float4* p0 = (const float4*)(Af + (size_t)(m0 + r0) * K + k0 + o0);
      const float4* p1 = (const float4*)(Af + (size_t)(m0 + r0 + 64) * K + k0 + o0);
      a0 = cvt8(p0[0], p0[1]);
      a1 = cvt8(p1[0], p1[1]);
    } else {
      const u16* Ab = (const u16*)Av;
      a0 = *(const us8*)(Ab + (size_t)(m0 + r0) * K + k0 + o0);
      a1 = *(const us8*)(Ab + (size_t)(m0 + r0 + 64) * K + k0 + o0);
    }
    b0 = *(const us8*)(Bt + (size_t)(n0 + r0) * K + k0 + o0);
    b1 = *(const us8*)(Bt + (size_t)(n0 + r0 + 64) * K + k0 + o0);
    __syncthreads();
    *(us8*)(&As[r0][o0]) = a0;
    *(us8*)(&As[r0 + 64][o0]) = a1;
    *(us8*)(&Bs[r0][o0]) = b0;
    *(us8*)(&Bs[r0 + 64][o0]) = b1;
    __syncthreads();
    us8 af[4], bfr[4];
#pragma unroll
    for (int i = 0; i < 4; i++)
      af[i] = *(const us8*)(&As[wm * 64 + i * 16 + lrow][lhalf * 8]);
#pragma unroll
    for (int j = 0; j < 4; j++)
      bfr[j] = *(const us8*)(&Bs[wn * 64 + j * 16 + lrow][lhalf * 8]);
#pragma unroll
    for (int i = 0; i < 4; i++)
#pragma unroll
      for (int j = 0; j < 4; j++) acc[i][j] = mfma16(af[i], bfr[j], acc[i][j]);
  }

#pragma unroll
  for (int i = 0; i < 4; i++) {
    const int rowb = m0 + wm * 64 + i * 16 + lhalf * 4;
#pragma unroll
    for (int j = 0; j < 4; j++) {
      const int col = n0 + wn * 64 + j * 16 + lrow;
      const float bv = bias[col];
#pragma unroll
      for (int r = 0; r < 4; r++) {
        float v = acc[i][j][r] + bv;
        if constexpr (F32OUT)
          ((float*)Cv)[(size_t)(rowb + r) * N + col] = v;
        else
          ((u16*)Cv)[(size_t)(rowb + r) * N + col] = to_bf16(v);
      }
    }
  }
}

// ---------------- flash attention, swapped-QK^T 32x32, LDS-staged K/V ------
// 4 waves/block share one (b,h); wave w owns q-rows [bx*128 + w*32, +32).
// Per j-tile the block stages K (32x64, 4KB) and V^T (64x32, 4KB) into LDS
// (double-buffered, XOR-swizzled), each thread moving one 16B chunk of each.
// Lane owns q = lane&31; S^T = mfma32(K, Q); O^T = mfma32(V^T, P^T).
// Softmax in exp2 domain with defer-rescale (T13).
__global__ __launch_bounds__(256, 4) void attn_fwd(
    const u16* __restrict__ Qp, const u16* __restrict__ Kp,
    const u16* __restrict__ Vt, const float* __restrict__ mask,
    u16* __restrict__ ctx) {
  const int b = blockIdx.z, h = blockIdx.y;
  const int t = threadIdx.x;
  const int wave = t >> 6, lane = t & 63;
  const int l31 = lane & 31, hi = lane >> 5;
  const int q0 = blockIdx.x * 128 + wave * 32;

  // layout: K bufs at 0 / 2048 elems, V bufs at 4096 / 6144; epilogue overlays.
  // (no pointer arrays into LDS — gfx950 rejects the addrspacecast initializer)
  __shared__ __align__(16) u16 smem[9216];   // 18432 B

  const u16* Qb = Qp + (size_t)(b * SEQ + q0) * D_MODEL + h * DKH;
  const u16* Kb = Kp + (size_t)(b * SEQ) * D_MODEL + h * DKH;
  const u16* Vb = Vt + (size_t)(b * NHEADS + h) * DKH * SEQ;
  const float* mb = mask + (size_t)b * SEQ;

  // staging coords: thread moves K chunk (kr, kc) and V chunk (vr, vc)
  const int kr = t >> 3, kc = t & 7;     // K: 32 rows x 8 chunks of 16B
  const int vr = t >> 2, vc = t & 3;     // V: 64 rows x 4 chunks of 16B
  const int kws = (kc ^ (kr & 7)) * 8;   // swizzled element offset in K row
  const int vws = (vc ^ (vr & 3)) * 8;   // swizzled element offset in V row

  us8 qf[4];
#pragma unroll
  for (int s = 0; s < 4; s++)
    qf[s] = *(const us8*)(Qb + (size_t)l31 * D_MODEL + s * 16 + hi * 8);

  float mrow = -1e30f, lsum = 0.f;
  f32x16 o0 = {}, o1 = {};

  // prologue: stage tile 0
  {
    us8 k0 = *(const us8*)(Kb + (size_t)kr * D_MODEL + kc * 8);
    us8 v0 = *(const us8*)(Vb + (size_t)vr * SEQ + vc * 8);
    *(us8*)&smem[kr * 64 + kws] = k0;
    *(us8*)&smem[4096 + vr * 32 + vws] = v0;
  }
  __syncthreads();

  int buf = 0;
  for (int j0 = 0; j0 < SEQ; j0 += 32) {
    u16* const ks = smem + buf * 2048;          // current K buffer
    u16* const vs = smem + 4096 + buf * 2048;   // current V buffer
    // issue next-tile staging loads (covered by this tile's compute)
    const bool more = (j0 + 32 < SEQ);
    us8 knext, vnext;
    if (more) {
      knext = *(const us8*)(Kb + (size_t)(j0 + 32 + kr) * D_MODEL + kc * 8);
      vnext = *(const us8*)(Vb + (size_t)vr * SEQ + j0 + 32 + vc * 8);
    }
    float4 mq[4];
#pragma unroll
    for (int t2 = 0; t2 < 4; t2++)
      mq[t2] = *(const float4*)(mb + j0 + 8 * t2 + 4 * hi);

    // K fragments from LDS (swizzled) -> S^T = K · Q
    f32x16 st = {};
#pragma unroll
    for (int s = 0; s < 4; s++) {
      us8 kf = *(const us8*)&ks[l31 * 64 + (((s * 2 + hi) ^ (l31 & 7)) * 8)];
      st = mfma32(kf, qf[s], st);
    }
    // V fragments from LDS early (latency covered by softmax)
    us8 vfr[4];
#pragma unroll
    for (int db = 0; db < 2; db++)
#pragma unroll
      for (int k2 = 0; k2 < 2; k2++)
        vfr[db * 2 + k2] = *(const us8*)&vs[(db * 32 + l31) * 32 +
                                            (((k2 * 2 + hi) ^ (l31 & 3)) * 8)];

    // logits in log2 domain; lane's kv(r) = (r&3) + 8*(r>>2) + 4*hi
    float sc[16];
#pragma unroll
    for (int r = 0; r < 16; r++) {
      const float* mqf = (const float*)&mq[r >> 2];
      sc[r] = fmaf(st[r], QK_SCALE2, mqf[r & 3] * MASK_SCALE2);
    }
    // max: in-lane tree + one cross-half shfl
    float mx = fmaxf(fmaxf(fmaxf(fmaxf(sc[0], sc[1]), fmaxf(sc[2], sc[3])),
                           fmaxf(fmaxf(sc[4], sc[5]), fmaxf(sc[6], sc[7]))),
                     fmaxf(fmaxf(fmaxf(sc[8], sc[9]), fmaxf(sc[10], sc[11])),
                           fmaxf(fmaxf(sc[12], sc[13]), fmaxf(sc[14], sc[15]))));
    mx = fmaxf(mx, __shfl_xor(mx, 32));
    // defer-rescale (T13)
    if (!__all(mx <= mrow + RESC_THR)) {
      const float mnew = fmaxf(mrow, mx);
      const float corr = __builtin_exp2f(mrow - mnew);
      mrow = mnew;
      lsum *= corr;
#pragma unroll
      for (int r = 0; r < 16; r++) { o0[r] *= corr; o1[r] *= corr; }
    }
    // exp2 + sum
    float p[16];
#pragma unroll
    for (int r = 0; r < 16; r++) p[r] = __builtin_exp2f(sc[r] - mrow);
    float rs = (((p[0] + p[1]) + (p[2] + p[3])) + ((p[4] + p[5]) + (p[6] + p[7])))
             + (((p[8] + p[9]) + (p[10] + p[11])) + ((p[12] + p[13]) + (p[14] + p[15])));
    rs += __shfl_xor(rs, 32);
    lsum += rs;
    // P^T -> B-fragments: pack bf16 pairs, cross-half shfl, select
    u32 w[8], sw[8];
#pragma unroll
    for (int tt = 0; tt < 8; tt++) w[tt] = pack_bf16(p[2 * tt], p[2 * tt + 1]);
#pragma unroll
    for (int tt = 0; tt < 8; tt++) sw[tt] = (u32)__shfl_xor((int)w[tt], 32);
    union { u32 uw[4]; us8 v; } pb0, pb1;
    pb0.uw[0] = hi ? sw[2] : w[0];  pb0.uw[1] = hi ? sw[3] : w[1];
    pb0.uw[2] = hi ? w[2] : sw[0];  pb0.uw[3] = hi ? w[3] : sw[1];
    pb1.uw[0] = hi ? sw[6] : w[4];  pb1.uw[1] = hi ? sw[7] : w[5];
    pb1.uw[2] = hi ? w[6] : sw[4];  pb1.uw[3] = hi ? w[7] : sw[5];
    // O^T += V^T · P^T
    o0 = mfma32(vfr[0], pb0.v, o0);
    o0 = mfma32(vfr[1], pb1.v, o0);
    o1 = mfma32(vfr[2], pb0.v, o1);
    o1 = mfma32(vfr[3], pb1.v, o1);
    // write next tile into the other buffer, then one barrier per tile
    if (more) {
      u16* const ksn = smem + (buf ^ 1) * 2048;
      u16* const vsn = smem + 4096 + (buf ^ 1) * 2048;
      *(us8*)&ksn[kr * 64 + kws] = knext;
      *(us8*)&vsn[vr * 32 + vws] = vnext;
    }
    __syncthreads();
    buf ^= 1;
  }

  const float inv = 1.0f / lsum;
  // epilogue overlays smem: per-wave [32][72] slice
  u16* pl = smem + wave * (32 * 72);
#pragma unroll
  for (int tt = 0; tt < 8; tt++) {
    const int r = 2 * tt;
    const int d0 = (r & 3) + 8 * (r >> 2) + 4 * hi;
    *(u32*)&pl[l31 * 72 + d0]      = pack_bf16(o0[r] * inv, o0[r + 1] * inv);
    *(u32*)&pl[l31 * 72 + 32 + d0] = pack_bf16(o1[r] * inv, o1[r + 1] * inv);
  }
  __syncthreads();
  u16* op = ctx + (size_t)(b * SEQ + q0) * D_MODEL + h * DKH;
#pragma unroll
  for (int pass = 0; pass < 4; pass++) {
    const int row = pass * 8 + (lane >> 3);
    const int c = (lane & 7) * 8;
    us8 vv = *(const us8*)&pl[row * 72 + c];
    *(us8*)(op + (size_t)row * D_MODEL + c) = vv;
  }
}

// ---------------------------------------------------------------------------
extern "C" void kernel_launch(void* const* d_in, const int* in_sizes, int n_in,
                              void* d_out, int out_size, void* d_ws, size_t ws_size,
                              hipStream_t stream) {
  const float* query = (const float*)d_in[0];
  const float* key   = (const float*)d_in[1];
  const float* value = (const float*)d_in[2];
  const float* mask  = (const float*)d_in[3];
  const float* Wq = (const float*)d_in[4];  const float* bq = (const float*)d_in[5];
  const float* Wk = (const float*)d_in[6];  const float* bk = (const float*)d_in[7];
  const float* Wv = (const float*)d_in[8];  const float* bv = (const float*)d_in[9];
  const float* Wo = (const float*)d_in[10]; const float* bo = (const float*)d_in[11];
  float* out = (float*)d_out;

  const size_t MB = 1ull << 20;
  char* ws = (char*)d_ws;
  u16* wtq = (u16*)(ws + 0 * MB);
  u16* wtk = (u16*)(ws + 2 * MB);
  u16* wtv = (u16*)(ws + 4 * MB);
  u16* wto = (u16*)(ws + 6 * MB);
  u16* Qp  = (u16*)(ws + 8 * MB);
  u16* Kp  = (u16*)(ws + 24 * MB);
  u16* ctx = (u16*)(ws + 40 * MB);
  u16* Vp = (u16*)d_out;                         // dead before final GEMM
  u16* Vt = Vp + (size_t)MTOT * D_MODEL;

  transpose_cvt_w<<<dim3(32, 32), 256, 0, stream>>>(Wq, wtq, D_MODEL, D_MODEL);
  transpose_cvt_w<<<dim3(32, 32), 256, 0, stream>>>(Wk, wtk, D_MODEL, D_MODEL);
  transpose_cvt_w<<<dim3(32, 32), 256, 0, stream>>>(Wv, wtv, D_MODEL, D_MODEL);
  transpose_cvt_w<<<dim3(32, 32), 256, 0, stream>>>(Wo, wto, D_MODEL, D_MODEL);

  dim3 ggrid(MTOT / 128, D_MODEL / 128);
  gemm_bt<true, false><<<ggrid, 256, 0, stream>>>((const void*)query, wtq, bq, (void*)Qp, D_MODEL, D_MODEL);
  gemm_bt<true, false><<<ggrid, 256, 0, stream>>>((const void*)key,   wtk, bk, (void*)Kp, D_MODEL, D_MODEL);
  gemm_bt<true, false><<<ggrid, 256, 0, stream>>>((const void*)value, wtv, bv, (void*)Vp, D_MODEL, D_MODEL);

  transpose_v_kernel<<<dim3(D_MODEL / 32, SEQ / 32, BATCH), 256, 0, stream>>>(Vp, Vt);

  attn_fwd<<<dim3(SEQ / 128, NHEADS, BATCH), 256, 0, stream>>>(Qp, Kp, Vt, mask, ctx);

  gemm_bt<false, true><<<ggrid, 256, 0, stream>>>((const void*)ctx, wto, bo, (void*)out, D_MODEL, D_MODEL);
}

// Round 7
// 451.264 us; speedup vs baseline: 1.3986x; 1.0176x over previous
//
#include <hip/hip_runtime.h>
#include <hip/hip_bf16.h>
#include <stdint.h>

#define D_MODEL 1024
#define NHEADS  16
#define DKH     64
#define SEQ     2048
#define BATCH   4
#define MTOT    (BATCH*SEQ)   // 8192

typedef unsigned short u16;
typedef uint32_t u32;
typedef __attribute__((ext_vector_type(8))) unsigned short us8;
typedef __attribute__((ext_vector_type(4))) float f32x4;
typedef __attribute__((ext_vector_type(16))) float f32x16;
typedef __attribute__((ext_vector_type(8))) __bf16 bf16x8;

#define LOG2E 1.4426950408889634f
#define QK_SCALE2 (0.125f * LOG2E)       // 1/sqrt(64) * log2(e)
#define MASK_SCALE2 (-1e9f * LOG2E)
#define RESC_THR 8.0f                    // defer-rescale threshold (log2 domain)

__device__ __forceinline__ u16 to_bf16(float f) {
  __bf16 h = (__bf16)f;            // RNE fptrunc
  return __builtin_bit_cast(u16, h);
}
__device__ __forceinline__ u32 pack_bf16(float lo, float hi) {
  return (u32)to_bf16(lo) | ((u32)to_bf16(hi) << 16);
}

__device__ __forceinline__ f32x4 mfma16(us8 a, us8 b, f32x4 c) {
  return __builtin_amdgcn_mfma_f32_16x16x32_bf16(
      __builtin_bit_cast(bf16x8, a), __builtin_bit_cast(bf16x8, b), c, 0, 0, 0);
}
__device__ __forceinline__ f32x16 mfma32(us8 a, us8 b, f32x16 c) {
  return __builtin_amdgcn_mfma_f32_32x32x16_bf16(
      __builtin_bit_cast(bf16x8, a), __builtin_bit_cast(bf16x8, b), c, 0, 0, 0);
}

__device__ __forceinline__ us8 cvt8(float4 x, float4 y) {
  us8 r;
  r[0] = to_bf16(x.x); r[1] = to_bf16(x.y); r[2] = to_bf16(x.z); r[3] = to_bf16(x.w);
  r[4] = to_bf16(y.x); r[5] = to_bf16(y.y); r[6] = to_bf16(y.z); r[7] = to_bf16(y.w);
  return r;
}

// async global->LDS, 16 B per lane (wave-uniform LDS base + lane*16)
__device__ __forceinline__ void gload16(const u16* g, u16* l) {
  __builtin_amdgcn_global_load_lds(
      (const __attribute__((address_space(1))) void*)g,
      (__attribute__((address_space(3))) void*)l, 16, 0, 0);
}

// ---------------- f32 -> bf16 convert (8 elems/thread) ----------------------
__global__ __launch_bounds__(256) void cvt_bf16(
    const float* __restrict__ in, u16* __restrict__ out) {
  const int i = (blockIdx.x * 256 + threadIdx.x) * 8;
  float4 a = *(const float4*)(in + i);
  float4 b = *(const float4*)(in + i + 4);
  *(us8*)(out + i) = cvt8(a, b);
}

// ---------------- mask pre-scale: mm = mask * (-1e9*log2e) ------------------
__global__ __launch_bounds__(256) void scale_mask(
    const float* __restrict__ m, float* __restrict__ mm, int n) {
  const int i = blockIdx.x * 256 + threadIdx.x;
  if (i < n) mm[i] = m[i] * MASK_SCALE2;
}

// ---------------- transpose+convert weight: W[K][N] f32 -> Wt[N][K] bf16 ----
__global__ __launch_bounds__(256) void transpose_cvt_w(
    const float* __restrict__ W, u16* __restrict__ Wt, int rows, int cols) {
  __shared__ float tile[32][33];
  const int c0 = blockIdx.x * 32, r0 = blockIdx.y * 32;
  const int tx = threadIdx.x & 31, ty = threadIdx.x >> 5;
#pragma unroll
  for (int yy = ty; yy < 32; yy += 8)
    tile[yy][tx] = W[(size_t)(r0 + yy) * cols + c0 + tx];
  __syncthreads();
#pragma unroll
  for (int yy = ty; yy < 32; yy += 8)
    Wt[(size_t)(c0 + yy) * rows + r0 + tx] = to_bf16(tile[tx][yy]);
}

// ---------------- transpose V: per b, Vp[S][1024] bf16 -> Vt[1024][S] bf16 --
__global__ __launch_bounds__(256) void transpose_v_kernel(
    const u16* __restrict__ Vp, u16* __restrict__ Vt) {
  __shared__ u16 tile[32][33];
  const int b = blockIdx.z;
  const int c0 = blockIdx.x * 32, r0 = blockIdx.y * 32;
  const u16* in = Vp + (size_t)b * SEQ * D_MODEL;
  u16* out = Vt + (size_t)b * D_MODEL * SEQ;
  const int tx = threadIdx.x & 31, ty = threadIdx.x >> 5;
#pragma unroll
  for (int yy = ty; yy < 32; yy += 8)
    tile[yy][tx] = in[(size_t)(r0 + yy) * D_MODEL + c0 + tx];
  __syncthreads();
#pragma unroll
  for (int yy = ty; yy < 32; yy += 8)
    out[(size_t)(c0 + yy) * SEQ + r0 + tx] = tile[tx][yy];
}

// ---------------- GEMM (m97 structure): C = A[M][K] * Bt[N][K]^T + bias -----
// 128x128 tile, BK=32, double-buffered LDS staged via global_load_lds,
// issue-next -> compute-current -> one barrier per K-step.
template <bool F32OUT>
__global__ __launch_bounds__(256) void gemm_bt(
    const u16* __restrict__ A, const u16* __restrict__ Bt,
    const float* __restrict__ bias, void* __restrict__ Cv, int N, int K) {
  __shared__ __align__(16) u16 As[2][128][32];
  __shared__ __align__(16) u16 Bs[2][128][32];
  const int m0 = blockIdx.x * 128, n0 = blockIdx.y * 128;
  const int t = threadIdx.x;
  const int lane = t & 63, wave = t >> 6;
  const int wm = wave >> 1, wn = wave & 1;
  const int lrow = lane & 15, lhalf = lane >> 4;

  const u16* Ab = A + (size_t)m0 * K;
  const u16* Bb = Bt + (size_t)n0 * K;
  // two 16B chunks per thread per tile: chunk c -> row c>>2, elem off (c&3)*8
  const int c0 = t,        r0_ = c0 >> 2, o0_ = (c0 & 3) << 3;
  const int c1 = 256 + t,  r1_ = c1 >> 2, o1_ = (c1 & 3) << 3;

  f32x4 acc[4][4];
#pragma unroll
  for (int i = 0; i < 4; i++)
#pragma unroll
    for (int j = 0; j < 4; j++) acc[i][j] = (f32x4){0.f, 0.f, 0.f, 0.f};

  // prologue: stage tile 0
  gload16(Ab + (size_t)r0_ * K + o0_, &As[0][r0_][o0_]);
  gload16(Ab + (size_t)r1_ * K + o1_, &As[0][r1_][o1_]);
  gload16(Bb + (size_t)r0_ * K + o0_, &Bs[0][r0_][o0_]);
  gload16(Bb + (size_t)r1_ * K + o1_, &Bs[0][r1_][o1_]);
  __syncthreads();   // implicit vmcnt(0) drain + barrier

  int buf = 0;
  for (int k0 = 0; k0 < K; k0 += 32) {
    const int kn = k0 + 32;
    if (kn < K) {   // issue next-tile staging; overlaps the MFMAs below
      gload16(Ab + (size_t)r0_ * K + kn + o0_, &As[buf ^ 1][r0_][o0_]);
      gload16(Ab + (size_t)r1_ * K + kn + o1_, &As[buf ^ 1][r1_][o1_]);
      gload16(Bb + (size_t)r0_ * K + kn + o0_, &Bs[buf ^ 1][r0_][o0_]);
      gload16(Bb + (size_t)r1_ * K + kn + o1_, &Bs[buf ^ 1][r1_][o1_]);
    }
    us8 af[4], bfr[4];
#pragma unroll
    for (int i = 0; i < 4; i++)
      af[i] = *(const us8*)(&As[buf][wm * 64 + i * 16 + lrow][lhalf * 8]);
#pragma unroll
    for (int j = 0; j < 4; j++)
      bfr[j] = *(const us8*)(&Bs[buf][wn * 64 + j * 16 + lrow][lhalf * 8]);
#pragma unroll
    for (int i = 0; i < 4; i++)
#pragma unroll
      for (int j = 0; j < 4; j++) acc[i][j] = mfma16(af[i], bfr[j], acc[i][j]);
    __syncthreads();  // staging of buf^1 done everywhere; buf reads drained
    buf ^= 1;
  }

#pragma unroll
  for (int i = 0; i < 4; i++) {
    const int rowb = m0 + wm * 64 + i * 16 + lhalf * 4;
#pragma unroll
    for (int j = 0; j < 4; j++) {
      const int col = n0 + wn * 64 + j * 16 + lrow;
      const float bv = bias[col];
#pragma unroll
      for (int r = 0; r < 4; r++) {
        float v = acc[i][j][r] + bv;
        if constexpr (F32OUT)
          ((float*)Cv)[(size_t)(rowb + r) * N + col] = v;
        else
          ((u16*)Cv)[(size_t)(rowb + r) * N + col] = to_bf16(v);
      }
    }
  }
}

// ---------------- flash attention, swapped-QK^T 32x32, LDS-staged K/V ------
// 4 waves/block share one (b,h); wave w owns q-rows [bx*128 + w*32, +32).
// mask2 is pre-scaled by -1e9*log2e. Otherwise identical to round-6 kernel.
__global__ __launch_bounds__(256, 4) void attn_fwd(
    const u16* __restrict__ Qp, const u16* __restrict__ Kp,
    const u16* __restrict__ Vt, const float* __restrict__ mask2,
    u16* __restrict__ ctx) {
  const int b = blockIdx.z, h = blockIdx.y;
  const int t = threadIdx.x;
  const int wave = t >> 6, lane = t & 63;
  const int l31 = lane & 31, hi = lane >> 5;
  const int q0 = blockIdx.x * 128 + wave * 32;

  __shared__ __align__(16) u16 smem[9216];   // 18432 B

  const u16* Qb = Qp + (size_t)(b * SEQ + q0) * D_MODEL + h * DKH;
  const u16* Kb = Kp + (size_t)(b * SEQ) * D_MODEL + h * DKH;
  const u16* Vb = Vt + (size_t)(b * NHEADS + h) * DKH * SEQ;
  const float* mb = mask2 + (size_t)b * SEQ;

  const int kr = t >> 3, kc = t & 7;     // K: 32 rows x 8 chunks of 16B
  const int vr = t >> 2, vc = t & 3;     // V: 64 rows x 4 chunks of 16B
  const int kws = (kc ^ (kr & 7)) * 8;
  const int vws = (vc ^ (vr & 3)) * 8;

  us8 qf[4];
#pragma unroll
  for (int s = 0; s < 4; s++)
    qf[s] = *(const us8*)(Qb + (size_t)l31 * D_MODEL + s * 16 + hi * 8);

  float mrow = -1e30f, lsum = 0.f;
  f32x16 o0 = {}, o1 = {};

  {
    us8 k0 = *(const us8*)(Kb + (size_t)kr * D_MODEL + kc * 8);
    us8 v0 = *(const us8*)(Vb + (size_t)vr * SEQ + vc * 8);
    *(us8*)&smem[kr * 64 + kws] = k0;
    *(us8*)&smem[4096 + vr * 32 + vws] = v0;
  }
  __syncthreads();

  int buf = 0;
  for (int j0 = 0; j0 < SEQ; j0 += 32) {
    u16* const ks = smem + buf * 2048;
    u16* const vs = smem + 4096 + buf * 2048;
    const bool more = (j0 + 32 < SEQ);
    us8 knext, vnext;
    if (more) {
      knext = *(const us8*)(Kb + (size_t)(j0 + 32 + kr) * D_MODEL + kc * 8);
      vnext = *(const us8*)(Vb + (size_t)vr * SEQ + j0 + 32 + vc * 8);
    }
    float4 mq[4];
#pragma unroll
    for (int t2 = 0; t2 < 4; t2++)
      mq[t2] = *(const float4*)(mb + j0 + 8 * t2 + 4 * hi);

    f32x16 st = {};
#pragma unroll
    for (int s = 0; s < 4; s++) {
      us8 kf = *(const us8*)&ks[l31 * 64 + (((s * 2 + hi) ^ (l31 & 7)) * 8)];
      st = mfma32(kf, qf[s], st);
    }
    us8 vfr[4];
#pragma unroll
    for (int db = 0; db < 2; db++)
#pragma unroll
      for (int k2 = 0; k2 < 2; k2++)
        vfr[db * 2 + k2] = *(const us8*)&vs[(db * 32 + l31) * 32 +
                                            (((k2 * 2 + hi) ^ (l31 & 3)) * 8)];

    float sc[16];
#pragma unroll
    for (int r = 0; r < 16; r++) {
      const float* mqf = (const float*)&mq[r >> 2];
      sc[r] = fmaf(st[r], QK_SCALE2, mqf[r & 3]);   // mask pre-scaled
    }
    float mx = fmaxf(fmaxf(fmaxf(fmaxf(sc[0], sc[1]), fmaxf(sc[2], sc[3])),
                           fmaxf(fmaxf(sc[4], sc[5]), fmaxf(sc[6], sc[7]))),
                     fmaxf(fmaxf(fmaxf(sc[8], sc[9]), fmaxf(sc[10], sc[11])),
                           fmaxf(fmaxf(sc[12], sc[13]), fmaxf(sc[14], sc[15]))));
    mx = fmaxf(mx, __shfl_xor(mx, 32));
    if (!__all(mx <= mrow + RESC_THR)) {
      const float mnew = fmaxf(mrow, mx);
      const float corr = __builtin_exp2f(mrow - mnew);
      mrow = mnew;
      lsum *= corr;
#pragma unroll
      for (int r = 0; r < 16; r++) { o0[r] *= corr; o1[r] *= corr; }
    }
    float p[16];
#pragma unroll
    for (int r = 0; r < 16; r++) p[r] = __builtin_exp2f(sc[r] - mrow);
    float rs = (((p[0] + p[1]) + (p[2] + p[3])) + ((p[4] + p[5]) + (p[6] + p[7])))
             + (((p[8] + p[9]) + (p[10] + p[11])) + ((p[12] + p[13]) + (p[14] + p[15])));
    rs += __shfl_xor(rs, 32);
    lsum += rs;
    u32 w[8], sw[8];
#pragma unroll
    for (int tt = 0; tt < 8; tt++) w[tt] = pack_bf16(p[2 * tt], p[2 * tt + 1]);
#pragma unroll
    for (int tt = 0; tt < 8; tt++) sw[tt] = (u32)__shfl_xor((int)w[tt], 32);
    union { u32 uw[4]; us8 v; } pb0, pb1;
    pb0.uw[0] = hi ? sw[2] : w[0];  pb0.uw[1] = hi ? sw[3] : w[1];
    pb0.uw[2] = hi ? w[2] : sw[0];  pb0.uw[3] = hi ? w[3] : sw[1];
    pb1.uw[0] = hi ? sw[6] : w[4];  pb1.uw[1] = hi ? sw[7] : w[5];
    pb1.uw[2] = hi ? w[6] : sw[4];  pb1.uw[3] = hi ? w[7] : sw[5];
    o0 = mfma32(vfr[0], pb0.v, o0);
    o0 = mfma32(vfr[1], pb1.v, o0);
    o1 = mfma32(vfr[2], pb0.v, o1);
    o1 = mfma32(vfr[3], pb1.v, o1);
    if (more) {
      u16* const ksn = smem + (buf ^ 1) * 2048;
      u16* const vsn = smem + 4096 + (buf ^ 1) * 2048;
      *(us8*)&ksn[kr * 64 + kws] = knext;
      *(us8*)&vsn[vr * 32 + vws] = vnext;
    }
    __syncthreads();
    buf ^= 1;
  }

  const float inv = 1.0f / lsum;
  u16* pl = smem + wave * (32 * 72);
#pragma unroll
  for (int tt = 0; tt < 8; tt++) {
    const int r = 2 * tt;
    const int d0 = (r & 3) + 8 * (r >> 2) + 4 * hi;
    *(u32*)&pl[l31 * 72 + d0]      = pack_bf16(o0[r] * inv, o0[r + 1] * inv);
    *(u32*)&pl[l31 * 72 + 32 + d0] = pack_bf16(o1[r] * inv, o1[r + 1] * inv);
  }
  __syncthreads();
  u16* op = ctx + (size_t)(b * SEQ + q0) * D_MODEL + h * DKH;
#pragma unroll
  for (int pass = 0; pass < 4; pass++) {
    const int row = pass * 8 + (lane >> 3);
    const int c = (lane & 7) * 8;
    us8 vv = *(const us8*)&pl[row * 72 + c];
    *(us8*)(op + (size_t)row * D_MODEL + c) = vv;
  }
}

// ---------------------------------------------------------------------------
extern "C" void kernel_launch(void* const* d_in, const int* in_sizes, int n_in,
                              void* d_out, int out_size, void* d_ws, size_t ws_size,
                              hipStream_t stream) {
  const float* query = (const float*)d_in[0];
  const float* key   = (const float*)d_in[1];
  const float* value = (const float*)d_in[2];
  const float* mask  = (const float*)d_in[3];
  const float* Wq = (const float*)d_in[4];  const float* bq = (const float*)d_in[5];
  const float* Wk = (const float*)d_in[6];  const float* bk = (const float*)d_in[7];
  const float* Wv = (const float*)d_in[8];  const float* bv = (const float*)d_in[9];
  const float* Wo = (const float*)d_in[10]; const float* bo = (const float*)d_in[11];
  float* out = (float*)d_out;

  const size_t MB = 1ull << 20;
  char* ws = (char*)d_ws;
  u16* wtq = (u16*)(ws + 0 * MB);
  u16* wtk = (u16*)(ws + 2 * MB);
  u16* wtv = (u16*)(ws + 4 * MB);
  u16* wto = (u16*)(ws + 6 * MB);
  float* mask2 = (float*)(ws + 8 * MB);        // 32 KB
  u16* Qp  = (u16*)(ws + 9 * MB);              // 16.8 MB
  u16* Kp  = (u16*)(ws + 26 * MB);             // 16.8 MB
  u16* VpCtx = (u16*)(ws + 43 * MB);           // Vp, later reused as ctx
  // d_out (33.55 MB) holds: S (bf16 cvt buffer, lower half) + Vt (upper half)
  u16* S  = (u16*)d_out;
  u16* Vt = S + (size_t)MTOT * D_MODEL;

  transpose_cvt_w<<<dim3(32, 32), 256, 0, stream>>>(Wq, wtq, D_MODEL, D_MODEL);
  transpose_cvt_w<<<dim3(32, 32), 256, 0, stream>>>(Wk, wtk, D_MODEL, D_MODEL);
  transpose_cvt_w<<<dim3(32, 32), 256, 0, stream>>>(Wv, wtv, D_MODEL, D_MODEL);
  transpose_cvt_w<<<dim3(32, 32), 256, 0, stream>>>(Wo, wto, D_MODEL, D_MODEL);
  scale_mask<<<dim3(32), 256, 0, stream>>>(mask, mask2, BATCH * SEQ);

  dim3 ggrid(MTOT / 128, D_MODEL / 128);
  const int cvtg = MTOT * D_MODEL / (256 * 8);   // 4096 blocks

  cvt_bf16<<<cvtg, 256, 0, stream>>>(query, S);
  gemm_bt<false><<<ggrid, 256, 0, stream>>>(S, wtq, bq, (void*)Qp, D_MODEL, D_MODEL);
  cvt_bf16<<<cvtg, 256, 0, stream>>>(key, S);
  gemm_bt<false><<<ggrid, 256, 0, stream>>>(S, wtk, bk, (void*)Kp, D_MODEL, D_MODEL);
  cvt_bf16<<<cvtg, 256, 0, stream>>>(value, S);
  gemm_bt<false><<<ggrid, 256, 0, stream>>>(S, wtv, bv, (void*)VpCtx, D_MODEL, D_MODEL);

  transpose_v_kernel<<<dim3(D_MODEL / 32, SEQ / 32, BATCH), 256, 0, stream>>>(VpCtx, Vt);

  attn_fwd<<<dim3(SEQ / 128, NHEADS, BATCH), 256, 0, stream>>>(Qp, Kp, Vt, mask2, VpCtx);

  gemm_bt<true><<<ggrid, 256, 0, stream>>>(VpCtx, wto, bo, (void*)out, D_MODEL, D_MODEL);
}

// Round 8
// 417.974 us; speedup vs baseline: 1.5100x; 1.0796x over previous
//
#include <hip/hip_runtime.h>
#include <hip/hip_bf16.h>
#include <stdint.h>

#define D_MODEL 1024
#define NHEADS  16
#define DKH     64
#define SEQ     2048
#define BATCH   4
#define MTOT    (BATCH*SEQ)   // 8192

typedef unsigned short u16;
typedef uint32_t u32;
typedef __attribute__((ext_vector_type(4))) unsigned short us4;
typedef __attribute__((ext_vector_type(8))) unsigned short us8;
typedef __attribute__((ext_vector_type(4))) float f32x4;
typedef __attribute__((ext_vector_type(16))) float f32x16;
typedef __attribute__((ext_vector_type(8))) __bf16 bf16x8;

#define LOG2E 1.4426950408889634f
#define QK_SCALE2 (0.125f * LOG2E)       // 1/sqrt(64) * log2(e)
#define MASK_SCALE2 (-1e9f * LOG2E)
#define RESC_THR 8.0f                    // defer-rescale threshold (log2 domain)

__device__ __forceinline__ u16 to_bf16(float f) {
  __bf16 h = (__bf16)f;            // RNE fptrunc
  return __builtin_bit_cast(u16, h);
}
__device__ __forceinline__ u32 pack_bf16(float lo, float hi) {
  return (u32)to_bf16(lo) | ((u32)to_bf16(hi) << 16);
}

__device__ __forceinline__ f32x4 mfma16(us8 a, us8 b, f32x4 c) {
  return __builtin_amdgcn_mfma_f32_16x16x32_bf16(
      __builtin_bit_cast(bf16x8, a), __builtin_bit_cast(bf16x8, b), c, 0, 0, 0);
}
__device__ __forceinline__ f32x16 mfma32(us8 a, us8 b, f32x16 c) {
  return __builtin_amdgcn_mfma_f32_32x32x16_bf16(
      __builtin_bit_cast(bf16x8, a), __builtin_bit_cast(bf16x8, b), c, 0, 0, 0);
}

__device__ __forceinline__ us8 cvt8(float4 x, float4 y) {
  us8 r;
  r[0] = to_bf16(x.x); r[1] = to_bf16(x.y); r[2] = to_bf16(x.z); r[3] = to_bf16(x.w);
  r[4] = to_bf16(y.x); r[5] = to_bf16(y.y); r[6] = to_bf16(y.z); r[7] = to_bf16(y.w);
  return r;
}

// async global->LDS, 16 B per lane (wave-uniform LDS base + lane*16)
__device__ __forceinline__ void gload16(const u16* g, u16* l) {
  __builtin_amdgcn_global_load_lds(
      (const __attribute__((address_space(1))) void*)g,
      (__attribute__((address_space(3))) void*)l, 16, 0, 0);
}

// ---------------- f32 -> bf16 convert (8 elems/thread) ----------------------
__global__ __launch_bounds__(256) void cvt_bf16(
    const float* __restrict__ in, u16* __restrict__ out) {
  const int i = (blockIdx.x * 256 + threadIdx.x) * 8;
  float4 a = *(const float4*)(in + i);
  float4 b = *(const float4*)(in + i + 4);
  *(us8*)(out + i) = cvt8(a, b);
}

// ---------------- mask pre-scale: mm = mask * (-1e9*log2e) ------------------
__global__ __launch_bounds__(256) void scale_mask(
    const float* __restrict__ m, float* __restrict__ mm, int n) {
  const int i = blockIdx.x * 256 + threadIdx.x;
  if (i < n) mm[i] = m[i] * MASK_SCALE2;
}

// ---------------- transpose+convert weight: W[K][N] f32 -> Wt[N][K] bf16 ----
__global__ __launch_bounds__(256) void transpose_cvt_w(
    const float* __restrict__ W, u16* __restrict__ Wt, int rows, int cols) {
  __shared__ float tile[32][33];
  const int c0 = blockIdx.x * 32, r0 = blockIdx.y * 32;
  const int tx = threadIdx.x & 31, ty = threadIdx.x >> 5;
#pragma unroll
  for (int yy = ty; yy < 32; yy += 8)
    tile[yy][tx] = W[(size_t)(r0 + yy) * cols + c0 + tx];
  __syncthreads();
#pragma unroll
  for (int yy = ty; yy < 32; yy += 8)
    Wt[(size_t)(c0 + yy) * rows + r0 + tx] = to_bf16(tile[tx][yy]);
}

// ---------------- batched projection GEMM ----------------------------------
// z selects one of 3 argument sets. C[M][1024] = A[M][1024] * Bt^T + bias.
// vt=0: row-major bf16 C. vt=1: write V^T layout Vt[b][col][s] (fuses the
// V transpose into the epilogue; 8B packed stores along s).
// m97 structure: 128x128 tile, BK=32, dbuf LDS via global_load_lds.
struct GArgs {
  const u16* A; const u16* Bt; const float* bias; u16* C; int vt;
};

__global__ __launch_bounds__(256) void gemm_proj(GArgs g0, GArgs g1, GArgs g2) {
  const GArgs g = (blockIdx.z == 0) ? g0 : (blockIdx.z == 1) ? g1 : g2;
  __shared__ __align__(16) u16 As[2][128][32];
  __shared__ __align__(16) u16 Bs[2][128][32];
  const int m0 = blockIdx.x * 128, n0 = blockIdx.y * 128;
  const int t = threadIdx.x;
  const int lane = t & 63, wave = t >> 6;
  const int wm = wave >> 1, wn = wave & 1;
  const int lrow = lane & 15, lhalf = lane >> 4;

  const u16* Ab = g.A + (size_t)m0 * D_MODEL;
  const u16* Bb = g.Bt + (size_t)n0 * D_MODEL;
  const int c0 = t,        r0_ = c0 >> 2, o0_ = (c0 & 3) << 3;
  const int c1 = 256 + t,  r1_ = c1 >> 2, o1_ = (c1 & 3) << 3;

  f32x4 acc[4][4];
#pragma unroll
  for (int i = 0; i < 4; i++)
#pragma unroll
    for (int j = 0; j < 4; j++) acc[i][j] = (f32x4){0.f, 0.f, 0.f, 0.f};

  gload16(Ab + (size_t)r0_ * D_MODEL + o0_, &As[0][r0_][o0_]);
  gload16(Ab + (size_t)r1_ * D_MODEL + o1_, &As[0][r1_][o1_]);
  gload16(Bb + (size_t)r0_ * D_MODEL + o0_, &Bs[0][r0_][o0_]);
  gload16(Bb + (size_t)r1_ * D_MODEL + o1_, &Bs[0][r1_][o1_]);
  __syncthreads();

  int buf = 0;
  for (int k0 = 0; k0 < D_MODEL; k0 += 32) {
    const int kn = k0 + 32;
    if (kn < D_MODEL) {
      gload16(Ab + (size_t)r0_ * D_MODEL + kn + o0_, &As[buf ^ 1][r0_][o0_]);
      gload16(Ab + (size_t)r1_ * D_MODEL + kn + o1_, &As[buf ^ 1][r1_][o1_]);
      gload16(Bb + (size_t)r0_ * D_MODEL + kn + o0_, &Bs[buf ^ 1][r0_][o0_]);
      gload16(Bb + (size_t)r1_ * D_MODEL + kn + o1_, &Bs[buf ^ 1][r1_][o1_]);
    }
    us8 af[4], bfr[4];
#pragma unroll
    for (int i = 0; i < 4; i++)
      af[i] = *(const us8*)(&As[buf][wm * 64 + i * 16 + lrow][lhalf * 8]);
#pragma unroll
    for (int j = 0; j < 4; j++)
      bfr[j] = *(const us8*)(&Bs[buf][wn * 64 + j * 16 + lrow][lhalf * 8]);
#pragma unroll
    for (int i = 0; i < 4; i++)
#pragma unroll
      for (int j = 0; j < 4; j++) acc[i][j] = mfma16(af[i], bfr[j], acc[i][j]);
    __syncthreads();
    buf ^= 1;
  }

  if (g.vt) {
    // transposed epilogue: Vt[b][col][s], s = token % SEQ, 4 consecutive s
#pragma unroll
    for (int i = 0; i < 4; i++) {
      const int m = m0 + wm * 64 + i * 16 + lhalf * 4;
      const int bb = m >> 11;            // / SEQ
      const int s  = m & 2047;           // % SEQ
#pragma unroll
      for (int j = 0; j < 4; j++) {
        const int col = n0 + wn * 64 + j * 16 + lrow;
        const float bv = g.bias[col];
        us4 v4;
#pragma unroll
        for (int r = 0; r < 4; r++) v4[r] = to_bf16(acc[i][j][r] + bv);
        *(us4*)(g.C + (size_t)bb * D_MODEL * SEQ + (size_t)col * SEQ + s) = v4;
      }
    }
  } else {
#pragma unroll
    for (int i = 0; i < 4; i++) {
      const int rowb = m0 + wm * 64 + i * 16 + lhalf * 4;
#pragma unroll
      for (int j = 0; j < 4; j++) {
        const int col = n0 + wn * 64 + j * 16 + lrow;
        const float bv = g.bias[col];
#pragma unroll
        for (int r = 0; r < 4; r++)
          g.C[(size_t)(rowb + r) * D_MODEL + col] = to_bf16(acc[i][j][r] + bv);
      }
    }
  }
}

// ---------------- output GEMM (f32 out): out = ctx * Wo^T + bo --------------
__global__ __launch_bounds__(256) void gemm_wo(
    const u16* __restrict__ A, const u16* __restrict__ Bt,
    const float* __restrict__ bias, float* __restrict__ C) {
  __shared__ __align__(16) u16 As[2][128][32];
  __shared__ __align__(16) u16 Bs[2][128][32];
  const int m0 = blockIdx.x * 128, n0 = blockIdx.y * 128;
  const int t = threadIdx.x;
  const int lane = t & 63, wave = t >> 6;
  const int wm = wave >> 1, wn = wave & 1;
  const int lrow = lane & 15, lhalf = lane >> 4;

  const u16* Ab = A + (size_t)m0 * D_MODEL;
  const u16* Bb = Bt + (size_t)n0 * D_MODEL;
  const int c0 = t,        r0_ = c0 >> 2, o0_ = (c0 & 3) << 3;
  const int c1 = 256 + t,  r1_ = c1 >> 2, o1_ = (c1 & 3) << 3;

  f32x4 acc[4][4];
#pragma unroll
  for (int i = 0; i < 4; i++)
#pragma unroll
    for (int j = 0; j < 4; j++) acc[i][j] = (f32x4){0.f, 0.f, 0.f, 0.f};

  gload16(Ab + (size_t)r0_ * D_MODEL + o0_, &As[0][r0_][o0_]);
  gload16(Ab + (size_t)r1_ * D_MODEL + o1_, &As[0][r1_][o1_]);
  gload16(Bb + (size_t)r0_ * D_MODEL + o0_, &Bs[0][r0_][o0_]);
  gload16(Bb + (size_t)r1_ * D_MODEL + o1_, &Bs[0][r1_][o1_]);
  __syncthreads();

  int buf = 0;
  for (int k0 = 0; k0 < D_MODEL; k0 += 32) {
    const int kn = k0 + 32;
    if (kn < D_MODEL) {
      gload16(Ab + (size_t)r0_ * D_MODEL + kn + o0_, &As[buf ^ 1][r0_][o0_]);
      gload16(Ab + (size_t)r1_ * D_MODEL + kn + o1_, &As[buf ^ 1][r1_][o1_]);
      gload16(Bb + (size_t)r0_ * D_MODEL + kn + o0_, &Bs[buf ^ 1][r0_][o0_]);
      gload16(Bb + (size_t)r1_ * D_MODEL + kn + o1_, &Bs[buf ^ 1][r1_][o1_]);
    }
    us8 af[4], bfr[4];
#pragma unroll
    for (int i = 0; i < 4; i++)
      af[i] = *(const us8*)(&As[buf][wm * 64 + i * 16 + lrow][lhalf * 8]);
#pragma unroll
    for (int j = 0; j < 4; j++)
      bfr[j] = *(const us8*)(&Bs[buf][wn * 64 + j * 16 + lrow][lhalf * 8]);
#pragma unroll
    for (int i = 0; i < 4; i++)
#pragma unroll
      for (int j = 0; j < 4; j++) acc[i][j] = mfma16(af[i], bfr[j], acc[i][j]);
    __syncthreads();
    buf ^= 1;
  }

#pragma unroll
  for (int i = 0; i < 4; i++) {
    const int rowb = m0 + wm * 64 + i * 16 + lhalf * 4;
#pragma unroll
    for (int j = 0; j < 4; j++) {
      const int col = n0 + wn * 64 + j * 16 + lrow;
      const float bv = bias[col];
#pragma unroll
      for (int r = 0; r < 4; r++)
        C[(size_t)(rowb + r) * D_MODEL + col] = acc[i][j][r] + bv;
    }
  }
}

// ---------------- flash attention, swapped-QK^T 32x32, LDS-staged K/V ------
__global__ __launch_bounds__(256, 4) void attn_fwd(
    const u16* __restrict__ Qp, const u16* __restrict__ Kp,
    const u16* __restrict__ Vt, const float* __restrict__ mask2,
    u16* __restrict__ ctx) {
  const int b = blockIdx.z, h = blockIdx.y;
  const int t = threadIdx.x;
  const int wave = t >> 6, lane = t & 63;
  const int l31 = lane & 31, hi = lane >> 5;
  const int q0 = blockIdx.x * 128 + wave * 32;

  __shared__ __align__(16) u16 smem[9216];   // 18432 B

  const u16* Qb = Qp + (size_t)(b * SEQ + q0) * D_MODEL + h * DKH;
  const u16* Kb = Kp + (size_t)(b * SEQ) * D_MODEL + h * DKH;
  const u16* Vb = Vt + (size_t)(b * NHEADS + h) * DKH * SEQ;
  const float* mb = mask2 + (size_t)b * SEQ;

  const int kr = t >> 3, kc = t & 7;     // K: 32 rows x 8 chunks of 16B
  const int vr = t >> 2, vc = t & 3;     // V: 64 rows x 4 chunks of 16B
  const int kws = (kc ^ (kr & 7)) * 8;
  const int vws = (vc ^ (vr & 3)) * 8;

  us8 qf[4];
#pragma unroll
  for (int s = 0; s < 4; s++)
    qf[s] = *(const us8*)(Qb + (size_t)l31 * D_MODEL + s * 16 + hi * 8);

  float mrow = -1e30f, lsum = 0.f;
  f32x16 o0 = {}, o1 = {};

  {
    us8 k0 = *(const us8*)(Kb + (size_t)kr * D_MODEL + kc * 8);
    us8 v0 = *(const us8*)(Vb + (size_t)vr * SEQ + vc * 8);
    *(us8*)&smem[kr * 64 + kws] = k0;
    *(us8*)&smem[4096 + vr * 32 + vws] = v0;
  }
  __syncthreads();

  int buf = 0;
  for (int j0 = 0; j0 < SEQ; j0 += 32) {
    u16* const ks = smem + buf * 2048;
    u16* const vs = smem + 4096 + buf * 2048;
    const bool more = (j0 + 32 < SEQ);
    us8 knext, vnext;
    if (more) {
      knext = *(const us8*)(Kb + (size_t)(j0 + 32 + kr) * D_MODEL + kc * 8);
      vnext = *(const us8*)(Vb + (size_t)vr * SEQ + j0 + 32 + vc * 8);
    }
    float4 mq[4];
#pragma unroll
    for (int t2 = 0; t2 < 4; t2++)
      mq[t2] = *(const float4*)(mb + j0 + 8 * t2 + 4 * hi);

    f32x16 st = {};
#pragma unroll
    for (int s = 0; s < 4; s++) {
      us8 kf = *(const us8*)&ks[l31 * 64 + (((s * 2 + hi) ^ (l31 & 7)) * 8)];
      st = mfma32(kf, qf[s], st);
    }
    us8 vfr[4];
#pragma unroll
    for (int db = 0; db < 2; db++)
#pragma unroll
      for (int k2 = 0; k2 < 2; k2++)
        vfr[db * 2 + k2] = *(const us8*)&vs[(db * 32 + l31) * 32 +
                                            (((k2 * 2 + hi) ^ (l31 & 3)) * 8)];

    float sc[16];
#pragma unroll
    for (int r = 0; r < 16; r++) {
      const float* mqf = (const float*)&mq[r >> 2];
      sc[r] = fmaf(st[r], QK_SCALE2, mqf[r & 3]);   // mask pre-scaled
    }
    float mx = fmaxf(fmaxf(fmaxf(fmaxf(sc[0], sc[1]), fmaxf(sc[2], sc[3])),
                           fmaxf(fmaxf(sc[4], sc[5]), fmaxf(sc[6], sc[7]))),
                     fmaxf(fmaxf(fmaxf(sc[8], sc[9]), fmaxf(sc[10], sc[11])),
                           fmaxf(fmaxf(sc[12], sc[13]), fmaxf(sc[14], sc[15]))));
    mx = fmaxf(mx, __shfl_xor(mx, 32));
    if (!__all(mx <= mrow + RESC_THR)) {
      const float mnew = fmaxf(mrow, mx);
      const float corr = __builtin_exp2f(mrow - mnew);
      mrow = mnew;
      lsum *= corr;
#pragma unroll
      for (int r = 0; r < 16; r++) { o0[r] *= corr; o1[r] *= corr; }
    }
    float p[16];
#pragma unroll
    for (int r = 0; r < 16; r++) p[r] = __builtin_exp2f(sc[r] - mrow);
    float rs = (((p[0] + p[1]) + (p[2] + p[3])) + ((p[4] + p[5]) + (p[6] + p[7])))
             + (((p[8] + p[9]) + (p[10] + p[11])) + ((p[12] + p[13]) + (p[14] + p[15])));
    rs += __shfl_xor(rs, 32);
    lsum += rs;
    u32 w[8], sw[8];
#pragma unroll
    for (int tt = 0; tt < 8; tt++) w[tt] = pack_bf16(p[2 * tt], p[2 * tt + 1]);
#pragma unroll
    for (int tt = 0; tt < 8; tt++) sw[tt] = (u32)__shfl_xor((int)w[tt], 32);
    union { u32 uw[4]; us8 v; } pb0, pb1;
    pb0.uw[0] = hi ? sw[2] : w[0];  pb0.uw[1] = hi ? sw[3] : w[1];
    pb0.uw[2] = hi ? w[2] : sw[0];  pb0.uw[3] = hi ? w[3] : sw[1];
    pb1.uw[0] = hi ? sw[6] : w[4];  pb1.uw[1] = hi ? sw[7] : w[5];
    pb1.uw[2] = hi ? w[6] : sw[4];  pb1.uw[3] = hi ? w[7] : sw[5];
    o0 = mfma32(vfr[0], pb0.v, o0);
    o0 = mfma32(vfr[1], pb1.v, o0);
    o1 = mfma32(vfr[2], pb0.v, o1);
    o1 = mfma32(vfr[3], pb1.v, o1);
    if (more) {
      u16* const ksn = smem + (buf ^ 1) * 2048;
      u16* const vsn = smem + 4096 + (buf ^ 1) * 2048;
      *(us8*)&ksn[kr * 64 + kws] = knext;
      *(us8*)&vsn[vr * 32 + vws] = vnext;
    }
    __syncthreads();
    buf ^= 1;
  }

  const float inv = 1.0f / lsum;
  u16* pl = smem + wave * (32 * 72);
#pragma unroll
  for (int tt = 0; tt < 8; tt++) {
    const int r = 2 * tt;
    const int d0 = (r & 3) + 8 * (r >> 2) + 4 * hi;
    *(u32*)&pl[l31 * 72 + d0]      = pack_bf16(o0[r] * inv, o0[r + 1] * inv);
    *(u32*)&pl[l31 * 72 + 32 + d0] = pack_bf16(o1[r] * inv, o1[r + 1] * inv);
  }
  __syncthreads();
  u16* op = ctx + (size_t)(b * SEQ + q0) * D_MODEL + h * DKH;
#pragma unroll
  for (int pass = 0; pass < 4; pass++) {
    const int row = pass * 8 + (lane >> 3);
    const int c = (lane & 7) * 8;
    us8 vv = *(const us8*)&pl[row * 72 + c];
    *(us8*)(op + (size_t)row * D_MODEL + c) = vv;
  }
}

// ---------------------------------------------------------------------------
extern "C" void kernel_launch(void* const* d_in, const int* in_sizes, int n_in,
                              void* d_out, int out_size, void* d_ws, size_t ws_size,
                              hipStream_t stream) {
  const float* query = (const float*)d_in[0];
  const float* key   = (const float*)d_in[1];
  const float* value = (const float*)d_in[2];
  const float* mask  = (const float*)d_in[3];
  const float* Wq = (const float*)d_in[4];  const float* bq = (const float*)d_in[5];
  const float* Wk = (const float*)d_in[6];  const float* bk = (const float*)d_in[7];
  const float* Wv = (const float*)d_in[8];  const float* bv = (const float*)d_in[9];
  const float* Wo = (const float*)d_in[10]; const float* bo = (const float*)d_in[11];
  float* out = (float*)d_out;

  const size_t MB = 1ull << 20;
  char* ws = (char*)d_ws;
  u16* wtq = (u16*)(ws + 0 * MB);
  u16* wtk = (u16*)(ws + 2 * MB);
  u16* wtv = (u16*)(ws + 4 * MB);
  u16* wto = (u16*)(ws + 6 * MB);
  float* mask2 = (float*)(ws + 8 * MB);
  u16* Qp  = (u16*)(ws + 9 * MB);
  u16* Kp  = (u16*)(ws + 26 * MB);
  u16* ctx = (u16*)(ws + 43 * MB);
  // d_out lower = Sv (bf16 value), upper = Vt (V transposed)
  u16* Sv = (u16*)d_out;
  u16* Vt = Sv + (size_t)MTOT * D_MODEL;

  transpose_cvt_w<<<dim3(32, 32), 256, 0, stream>>>(Wq, wtq, D_MODEL, D_MODEL);
  transpose_cvt_w<<<dim3(32, 32), 256, 0, stream>>>(Wk, wtk, D_MODEL, D_MODEL);
  transpose_cvt_w<<<dim3(32, 32), 256, 0, stream>>>(Wv, wtv, D_MODEL, D_MODEL);
  transpose_cvt_w<<<dim3(32, 32), 256, 0, stream>>>(Wo, wto, D_MODEL, D_MODEL);
  scale_mask<<<dim3(32), 256, 0, stream>>>(mask, mask2, BATCH * SEQ);

  dim3 ggrid(MTOT / 128, D_MODEL / 128);
  const int cvtg = MTOT * D_MODEL / (256 * 8);   // 4096 blocks

  const bool full = ws_size >= 94 * MB;
  if (full) {
    // 3-way batched projections: Sq(ws+60), Sk(ws+77), Sv(d_out lower)
    u16* Sq = (u16*)(ws + 60 * MB);
    u16* Sk = (u16*)(ws + 77 * MB);
    cvt_bf16<<<cvtg, 256, 0, stream>>>(query, Sq);
    cvt_bf16<<<cvtg, 256, 0, stream>>>(key,   Sk);
    cvt_bf16<<<cvtg, 256, 0, stream>>>(value, Sv);
    GArgs gq = { Sq, wtq, bq, Qp, 0 };
    GArgs gk = { Sk, wtk, bk, Kp, 0 };
    GArgs gv = { Sv, wtv, bv, Vt, 1 };
    gemm_proj<<<dim3(MTOT / 128, D_MODEL / 128, 3), 256, 0, stream>>>(gq, gk, gv);
  } else {
    // 2+1 inside 60MB: Sq shares ctx slot (dead before attn writes ctx);
    // Sk then Sv share d_out lower.
    u16* Sq = ctx;
    u16* Sk = Sv;
    cvt_bf16<<<cvtg, 256, 0, stream>>>(query, Sq);
    cvt_bf16<<<cvtg, 256, 0, stream>>>(key,   Sk);
    GArgs gq = { Sq, wtq, bq, Qp, 0 };
    GArgs gk = { Sk, wtk, bk, Kp, 0 };
    gemm_proj<<<dim3(MTOT / 128, D_MODEL / 128, 2), 256, 0, stream>>>(gq, gk, gk);
    cvt_bf16<<<cvtg, 256, 0, stream>>>(value, Sv);
    GArgs gv = { Sv, wtv, bv, Vt, 1 };
    gemm_proj<<<dim3(MTOT / 128, D_MODEL / 128, 1), 256, 0, stream>>>(gv, gv, gv);
  }

  attn_fwd<<<dim3(SEQ / 128, NHEADS, BATCH), 256, 0, stream>>>(Qp, Kp, Vt, mask2, ctx);

  gemm_wo<<<ggrid, 256, 0, stream>>>(ctx, wto, bo, out);
}